// Round 1
// baseline (242.811 us; speedup 1.0000x reference)
//
#include <hip/hip_runtime.h>

// DirichletLoss: ball-query (r=0.15, K=32) + 0.5*mean_i sum_k (f_i - f_nei)^2
// pos: [B,N,3] f32, f: [B,N] f32, out: scalar f32.
// Strategy: one wave (64 lanes) per query point. Brute-force scan of the
// batch's N candidates; compact in-radius (d2, fdiff2, idx) into LDS via
// ballot-prefix; rank-select K smallest by (d2, idx); reduce; atomicAdd.

#define BQ_K 32
#define CAP 512            // max buffered in-radius candidates per query
#define WAVES_PER_BLOCK 4  // block = 256 threads

__global__ void dl_zero_out(float* out) { out[0] = 0.0f; }

__global__ __launch_bounds__(256) void dirichlet_kernel(
    const float* __restrict__ pos, const float* __restrict__ f,
    float* __restrict__ out, int B, int N, float r2, float scale)
{
    __shared__ float s_d2 [WAVES_PER_BLOCK][CAP];
    __shared__ float s_fd2[WAVES_PER_BLOCK][CAP];
    __shared__ int   s_idx[WAVES_PER_BLOCK][CAP];
    __shared__ float s_wavesum[WAVES_PER_BLOCK];

    const int lane = threadIdx.x & 63;
    const int wave = threadIdx.x >> 6;
    const long long q = (long long)blockIdx.x * WAVES_PER_BLOCK + wave;
    const long long total = (long long)B * N;

    float sum = 0.0f;
    if (q < total) {
        const int b = (int)(q / N);
        const int i = (int)(q % N);
        const float* posb = pos + (size_t)b * N * 3;
        const float* fb   = f   + (size_t)b * N;

        const float px = posb[(size_t)i * 3 + 0];
        const float py = posb[(size_t)i * 3 + 1];
        const float pz = posb[(size_t)i * 3 + 2];
        const float fi = fb[i];

        // --- collect in-radius candidates into LDS (ballot compaction) ---
        int count = 0;
        for (int j0 = 0; j0 < N; j0 += 64) {
            const int j = j0 + lane;  // N % 64 == 0, always valid
            const float dx = posb[(size_t)j * 3 + 0] - px;
            const float dy = posb[(size_t)j * 3 + 1] - py;
            const float dz = posb[(size_t)j * 3 + 2] - pz;
            const float d2 = dx * dx + dy * dy + dz * dz;
            const bool in = (d2 <= r2);
            const unsigned long long mask = __ballot(in);
            const int off =
                count + __popcll(mask & ((1ULL << lane) - 1ULL));
            if (in && off < CAP) {
                s_d2 [wave][off] = d2;
                const float fd = fi - fb[j];
                s_fd2[wave][off] = fd * fd;
                s_idx[wave][off] = j;
            }
            count += __popcll(mask);
        }
        if (count > CAP) count = CAP;

        // wave-internal LDS produce->consume; lockstep wave, but make the
        // compiler order it (and all waves hit this barrier uniformly below)
        const int M = count;
        __syncthreads();

        // --- select K smallest by (d2, idx), sum fdiff^2 ---
        if (M <= BQ_K) {
            for (int e = lane; e < M; e += 64) sum += s_fd2[wave][e];
        } else {
            for (int e = lane; e < M; e += 64) {
                const float d2e = s_d2[wave][e];
                const int   ie  = s_idx[wave][e];
                int rank = 0;
                for (int m = 0; m < M; ++m) {
                    const float d2m = s_d2[wave][m];
                    rank += (d2m < d2e) ||
                            (d2m == d2e && s_idx[wave][m] < ie);
                }
                if (rank < BQ_K) sum += s_fd2[wave][e];
            }
        }
    } else {
        __syncthreads();  // keep barrier uniform across block
    }

    // --- wave reduce ---
    for (int o = 32; o > 0; o >>= 1) sum += __shfl_down(sum, o, 64);
    if (lane == 0) s_wavesum[wave] = sum;
    __syncthreads();
    if (threadIdx.x == 0) {
        float bs = 0.0f;
        for (int w = 0; w < WAVES_PER_BLOCK; ++w) bs += s_wavesum[w];
        atomicAdd(out, bs * scale);
    }
}

extern "C" void kernel_launch(void* const* d_in, const int* in_sizes, int n_in,
                              void* d_out, int out_size, void* d_ws, size_t ws_size,
                              hipStream_t stream) {
    const float* pos = (const float*)d_in[0];  // [B,N,3]
    const float* f   = (const float*)d_in[1];  // [B,N]
    float* out = (float*)d_out;

    const int N = 4096;
    const int B = in_sizes[1] / N;  // 8
    const float r2 = 0.15f * 0.15f;
    const float scale = 0.5f / (float)((long long)B * N);

    dl_zero_out<<<1, 1, 0, stream>>>(out);

    const long long total = (long long)B * N;
    const int blocks = (int)((total + WAVES_PER_BLOCK - 1) / WAVES_PER_BLOCK);
    dirichlet_kernel<<<blocks, 256, 0, stream>>>(pos, f, out, B, N, r2, scale);
}

// Round 2
// 199.709 us; speedup vs baseline: 1.2158x; 1.2158x over previous
//
#include <hip/hip_runtime.h>

// DirichletLoss: ball-query (r=0.15, K=32) + 0.5*mean_i sum_k (f_i - f_nei)^2
// pos: [B,N,3] f32, f: [B,N] f32, out: scalar f32.
//
// R2 strategy: per-batch 6^3 spatial hash (cell 1/6 >= r), counting-sort
// points into cell-bucketed SoA arrays in d_ws, then one wave per query
// scanning its 27-cell neighborhood as 9 contiguous ranges. Ballot-compact
// in-radius (d2, fd2, oidx) into LDS, rank-select K smallest by (d2, oidx),
// reduce, one atomicAdd per block.

#define BQ_K 32
#define CAP 256            // max buffered in-radius candidates (E[M]~58)
#define WPB 4              // waves per block (block = 256)
#define G 6
#define NC (G * G * G)     // 216 cells

__device__ __forceinline__ int cell_coord(float x) {
    int c = (int)(x * (float)G);
    return c < 0 ? 0 : (c > G - 1 ? G - 1 : c);
}

__global__ void dl_init(int* cnt, float* out, int total_cells) {
    int t = blockIdx.x * blockDim.x + threadIdx.x;
    if (t < total_cells) cnt[t] = 0;
    if (t == 0) out[0] = 0.0f;
}

__global__ void dl_count(const float* __restrict__ pos, int* __restrict__ cnt,
                         int B, int N) {
    int t = blockIdx.x * blockDim.x + threadIdx.x;
    if (t >= B * N) return;
    int b = t / N;
    int ix = cell_coord(pos[(size_t)t * 3 + 0]);
    int iy = cell_coord(pos[(size_t)t * 3 + 1]);
    int iz = cell_coord(pos[(size_t)t * 3 + 2]);
    atomicAdd(&cnt[b * NC + (iz * G + iy) * G + ix], 1);
}

// serial per-batch exclusive scan (216 cells); reuses cnt as scatter cursor
__global__ void dl_prefix(int* __restrict__ cnt, int* __restrict__ cs, int B) {
    int b = blockIdx.x * blockDim.x + threadIdx.x;
    if (b >= B) return;
    int acc = 0;
    for (int c = 0; c < NC; ++c) {
        int v = cnt[b * NC + c];
        cs[b * (NC + 1) + c] = acc;
        cnt[b * NC + c] = acc;   // cursor for scatter
        acc += v;
    }
    cs[b * (NC + 1) + NC] = acc; // == N
}

__global__ void dl_scatter(const float* __restrict__ pos, const float* __restrict__ f,
                           int* __restrict__ cur,
                           float* __restrict__ px, float* __restrict__ py,
                           float* __restrict__ pz, float* __restrict__ fs,
                           int* __restrict__ oidx, int B, int N) {
    int t = blockIdx.x * blockDim.x + threadIdx.x;
    if (t >= B * N) return;
    int b = t / N;
    int i = t - b * N;
    float x = pos[(size_t)t * 3 + 0];
    float y = pos[(size_t)t * 3 + 1];
    float z = pos[(size_t)t * 3 + 2];
    int c = (cell_coord(z) * G + cell_coord(y)) * G + cell_coord(x);
    int slot = atomicAdd(&cur[b * NC + c], 1);
    int dst = b * N + slot;
    px[dst] = x; py[dst] = y; pz[dst] = z;
    fs[dst] = f[t];
    oidx[dst] = i;
}

__global__ __launch_bounds__(256) void dl_main(
    const float* __restrict__ pos, const float* __restrict__ f,
    const int* __restrict__ cs,
    const float* __restrict__ px, const float* __restrict__ py,
    const float* __restrict__ pz, const float* __restrict__ fs,
    const int* __restrict__ oidx,
    float* __restrict__ out, int B, int N, float r2, float scale)
{
    __shared__ float s_d2 [WPB][CAP];
    __shared__ float s_fd2[WPB][CAP];
    __shared__ int   s_ix [WPB][CAP];
    __shared__ float s_wavesum[WPB];

    const int lane = threadIdx.x & 63;
    const int wave = threadIdx.x >> 6;
    const int q = blockIdx.x * WPB + wave;       // grid sized exactly B*N/WPB
    const int b = q / N;

    const float qx = pos[(size_t)q * 3 + 0];
    const float qy = pos[(size_t)q * 3 + 1];
    const float qz = pos[(size_t)q * 3 + 2];
    const float fi = f[q];

    const int cx = cell_coord(qx);
    const int cy = cell_coord(qy);
    const int cz = cell_coord(qz);

    const float* pxb = px + (size_t)b * N;
    const float* pyb = py + (size_t)b * N;
    const float* pzb = pz + (size_t)b * N;
    const float* fsb = fs + (size_t)b * N;
    const int*   oib = oidx + (size_t)b * N;
    const int*   csb = cs + b * (NC + 1);

    const int x0 = cx > 0 ? cx - 1 : 0;
    const int x1 = cx < G - 1 ? cx + 1 : G - 1;

    // --- scan 27-neighborhood as up to 9 contiguous ranges ---
    int count = 0;
    for (int iz = (cz > 0 ? cz - 1 : 0); iz <= (cz < G - 1 ? cz + 1 : G - 1); ++iz) {
        for (int iy = (cy > 0 ? cy - 1 : 0); iy <= (cy < G - 1 ? cy + 1 : G - 1); ++iy) {
            const int row = (iz * G + iy) * G;
            const int beg = csb[row + x0];
            const int end = csb[row + x1 + 1];
            for (int base = beg; base < end; base += 64) {
                const int jj = base + lane;
                bool in = false;
                float d2 = 0.0f, fd2 = 0.0f;
                int oj = 0;
                if (jj < end) {
                    const float dx = pxb[jj] - qx;
                    const float dy = pyb[jj] - qy;
                    const float dz = pzb[jj] - qz;
                    d2 = dx * dx + dy * dy + dz * dz;
                    if (d2 <= r2) {
                        in = true;
                        const float fd = fi - fsb[jj];
                        fd2 = fd * fd;
                        oj = oib[jj];
                    }
                }
                const unsigned long long mask = __ballot(in);
                const int off = count + __popcll(mask & ((1ULL << lane) - 1ULL));
                if (in && off < CAP) {
                    s_d2 [wave][off] = d2;
                    s_fd2[wave][off] = fd2;
                    s_ix [wave][off] = oj;
                }
                count += __popcll(mask);
            }
        }
    }
    const int M = count < CAP ? count : CAP;

    __syncthreads();   // order wave-local LDS writes before cross-lane reads

    // --- select K smallest by (d2, oidx), sum fdiff^2 ---
    float sum = 0.0f;
    if (M <= BQ_K) {
        for (int e = lane; e < M; e += 64) sum += s_fd2[wave][e];
    } else {
        for (int e = lane; e < M; e += 64) {
            const float d2e = s_d2[wave][e];
            const int   ie  = s_ix[wave][e];
            int rank = 0;
            for (int m = 0; m < M; ++m) {
                const float d2m = s_d2[wave][m];
                rank += (d2m < d2e) || (d2m == d2e && s_ix[wave][m] < ie);
            }
            if (rank < BQ_K) sum += s_fd2[wave][e];
        }
    }

    // --- reduce ---
    for (int o = 32; o > 0; o >>= 1) sum += __shfl_down(sum, o, 64);
    if (lane == 0) s_wavesum[wave] = sum;
    __syncthreads();
    if (threadIdx.x == 0) {
        float bs = 0.0f;
        for (int w = 0; w < WPB; ++w) bs += s_wavesum[w];
        atomicAdd(out, bs * scale);
    }
}

// ---------------- round-1 brute-force fallback (if ws too small) -----------
#define FCAP 512
__global__ __launch_bounds__(256) void dirichlet_bf(
    const float* __restrict__ pos, const float* __restrict__ f,
    float* __restrict__ out, int B, int N, float r2, float scale)
{
    __shared__ float s_d2 [WPB][FCAP];
    __shared__ float s_fd2[WPB][FCAP];
    __shared__ int   s_idx[WPB][FCAP];
    __shared__ float s_wavesum[WPB];

    const int lane = threadIdx.x & 63;
    const int wave = threadIdx.x >> 6;
    const int q = blockIdx.x * WPB + wave;
    const int b = q / N;
    const float* posb = pos + (size_t)b * N * 3;
    const float* fb   = f + (size_t)b * N;
    const float px = posb[(size_t)(q - b * N) * 3 + 0];
    const float py = posb[(size_t)(q - b * N) * 3 + 1];
    const float pz = posb[(size_t)(q - b * N) * 3 + 2];
    const float fi = f[q];

    int count = 0;
    for (int j0 = 0; j0 < N; j0 += 64) {
        const int j = j0 + lane;
        const float dx = posb[(size_t)j * 3 + 0] - px;
        const float dy = posb[(size_t)j * 3 + 1] - py;
        const float dz = posb[(size_t)j * 3 + 2] - pz;
        const float d2 = dx * dx + dy * dy + dz * dz;
        const bool in = (d2 <= r2);
        const unsigned long long mask = __ballot(in);
        const int off = count + __popcll(mask & ((1ULL << lane) - 1ULL));
        if (in && off < FCAP) {
            s_d2 [wave][off] = d2;
            const float fd = fi - fb[j];
            s_fd2[wave][off] = fd * fd;
            s_idx[wave][off] = j;
        }
        count += __popcll(mask);
    }
    const int M = count < FCAP ? count : FCAP;
    __syncthreads();

    float sum = 0.0f;
    if (M <= BQ_K) {
        for (int e = lane; e < M; e += 64) sum += s_fd2[wave][e];
    } else {
        for (int e = lane; e < M; e += 64) {
            const float d2e = s_d2[wave][e];
            const int   ie  = s_idx[wave][e];
            int rank = 0;
            for (int m = 0; m < M; ++m) {
                const float d2m = s_d2[wave][m];
                rank += (d2m < d2e) || (d2m == d2e && s_idx[wave][m] < ie);
            }
            if (rank < BQ_K) sum += s_fd2[wave][e];
        }
    }
    for (int o = 32; o > 0; o >>= 1) sum += __shfl_down(sum, o, 64);
    if (lane == 0) s_wavesum[wave] = sum;
    __syncthreads();
    if (threadIdx.x == 0) {
        float bs = 0.0f;
        for (int w = 0; w < WPB; ++w) bs += s_wavesum[w];
        atomicAdd(out, bs * scale);
    }
}

extern "C" void kernel_launch(void* const* d_in, const int* in_sizes, int n_in,
                              void* d_out, int out_size, void* d_ws, size_t ws_size,
                              hipStream_t stream) {
    const float* pos = (const float*)d_in[0];  // [B,N,3]
    const float* f   = (const float*)d_in[1];  // [B,N]
    float* out = (float*)d_out;

    const int N = 4096;
    const int B = in_sizes[1] / N;  // 8
    const float r2 = 0.15f * 0.15f;
    const float scale = 0.5f / (float)((long long)B * N);
    const int total = B * N;

    // workspace layout (all 4-byte elems)
    size_t n_cnt = (size_t)B * NC;
    size_t n_cs  = (size_t)B * (NC + 1);
    size_t need  = (n_cnt + n_cs + 5 * (size_t)total) * sizeof(int);

    if (ws_size < need) {
        dl_init<<<1, 64, 0, stream>>>((int*)d_ws, out, 0);
        dirichlet_bf<<<total / WPB, 256, 0, stream>>>(pos, f, out, B, N, r2, scale);
        return;
    }

    int*   cnt  = (int*)d_ws;
    int*   cs   = cnt + n_cnt;
    float* px   = (float*)(cs + n_cs);
    float* py   = px + total;
    float* pz   = py + total;
    float* fs   = pz + total;
    int*   oidx = (int*)(fs + total);

    dl_init   <<<(B * NC + 255) / 256, 256, 0, stream>>>(cnt, out, B * NC);
    dl_count  <<<(total + 255) / 256, 256, 0, stream>>>(pos, cnt, B, N);
    dl_prefix <<<1, 64, 0, stream>>>(cnt, cs, B);
    dl_scatter<<<(total + 255) / 256, 256, 0, stream>>>(pos, f, cnt, px, py, pz, fs, oidx, B, N);
    dl_main   <<<total / WPB, 256, 0, stream>>>(pos, f, cs, px, py, pz, fs, oidx,
                                                out, B, N, r2, scale);
}

// Round 3
// 131.711 us; speedup vs baseline: 1.8435x; 1.5163x over previous
//
#include <hip/hip_runtime.h>

// DirichletLoss: ball-query (r=0.15, K=32) + 0.5*mean_i sum_k (f_i - f_nei)^2
// pos: [B,N,3] f32, f: [B,N] f32, out: scalar f32.
//
// R3: counting-sort points into a 6^3 grid (cell 1/6 >= r). One workgroup per
// (batch, cell): stage the 27-cell neighborhood into LDS once (float4 SoA,
// sentinel-padded to x64), then each wave takes one query from the cell's own
// bucket, scans LDS candidates, ballot-compacts (d2,fd2) into a per-wave
// buffer, rank-selects K smallest d2 via register-broadcast (__shfl), and
// accumulates. One atomicAdd per block. Tie-break by index dropped (fp32 d2
// ties at the K boundary contribute <=1e-4 vs 0.61 threshold).
//
// Capacity proofs (Binomial tails): neighborhood <= 768 (mean 512, sd 21,
// +12sigma); in-ball M <= 128 (mean 58, sd 7.6, +9.3sigma).

#define BQ_K 32
#define CAP 128            // per-wave in-ball buffer
#define WPB 4              // waves per block (block = 256)
#define G 6
#define NC (G * G * G)     // 216 cells
#define CAPC 768           // staged neighborhood cap
#define CAPC_PAD (CAPC + 64)

__device__ __forceinline__ int cell_coord(float x) {
    int c = (int)(x * (float)G);
    return c < 0 ? 0 : (c > G - 1 ? G - 1 : c);
}

__global__ void dl_init(int* cnt, float* out, int total_cells) {
    int t = blockIdx.x * blockDim.x + threadIdx.x;
    if (t < total_cells) cnt[t] = 0;
    if (t == 0) out[0] = 0.0f;
}

__global__ void dl_count(const float* __restrict__ pos, int* __restrict__ cnt,
                         int B, int N) {
    int t = blockIdx.x * blockDim.x + threadIdx.x;
    if (t >= B * N) return;
    int b = t / N;
    int ix = cell_coord(pos[(size_t)t * 3 + 0]);
    int iy = cell_coord(pos[(size_t)t * 3 + 1]);
    int iz = cell_coord(pos[(size_t)t * 3 + 2]);
    atomicAdd(&cnt[b * NC + (iz * G + iy) * G + ix], 1);
}

// per-batch exclusive scan over 216 cells via wave-shuffle (one wave/batch);
// cnt is overwritten with the exclusive prefix to serve as scatter cursor.
__global__ __launch_bounds__(64) void dl_prefix(int* __restrict__ cnt,
                                                int* __restrict__ cs, int B) {
    const int b = blockIdx.x;
    const int lane = threadIdx.x;
    int* cb = cnt + b * NC;
    int* csb = cs + b * (NC + 1);
    int carry = 0;
    for (int base = 0; base < NC; base += 64) {
        const int idx = base + lane;
        const int v = (idx < NC) ? cb[idx] : 0;
        int x = v;
        for (int o = 1; o < 64; o <<= 1) {
            int y = __shfl_up(x, o, 64);
            if (lane >= o) x += y;
        }
        const int excl = carry + x - v;
        if (idx < NC) { csb[idx] = excl; cb[idx] = excl; }
        carry += __shfl(x, 63, 64);
    }
    if (lane == 0) csb[NC] = carry;  // == N
}

__global__ void dl_scatter(const float* __restrict__ pos, const float* __restrict__ f,
                           int* __restrict__ cur,
                           float* __restrict__ px, float* __restrict__ py,
                           float* __restrict__ pz, float* __restrict__ fs,
                           int B, int N) {
    int t = blockIdx.x * blockDim.x + threadIdx.x;
    if (t >= B * N) return;
    int b = t / N;
    float x = pos[(size_t)t * 3 + 0];
    float y = pos[(size_t)t * 3 + 1];
    float z = pos[(size_t)t * 3 + 2];
    int c = (cell_coord(z) * G + cell_coord(y)) * G + cell_coord(x);
    int slot = atomicAdd(&cur[b * NC + c], 1);
    int dst = b * N + slot;
    px[dst] = x; py[dst] = y; pz[dst] = z;
    fs[dst] = f[t];
}

__global__ __launch_bounds__(256) void dl_main(
    const int* __restrict__ cs,
    const float* __restrict__ px, const float* __restrict__ py,
    const float* __restrict__ pz, const float* __restrict__ fs,
    float* __restrict__ out, int N, float r2, float scale)
{
    __shared__ float4 s_cand[CAPC_PAD];
    __shared__ float2 s_sel[WPB][CAP];
    __shared__ float  s_wsum[WPB];

    const int bc = blockIdx.x;           // b*NC + c
    const int b  = bc / NC;
    const int c  = bc - b * NC;
    const int* csb = cs + b * (NC + 1);
    const int qbeg = csb[c];
    const int qend = csb[c + 1];
    if (qbeg == qend) return;            // uniform: whole block exits pre-sync

    const int cx = c % G, cy = (c / G) % G, cz = c / (G * G);
    const int x0 = cx > 0 ? cx - 1 : 0, x1 = cx < G - 1 ? cx + 1 : G - 1;
    const int y0 = cy > 0 ? cy - 1 : 0, y1 = cy < G - 1 ? cy + 1 : G - 1;
    const int z0 = cz > 0 ? cz - 1 : 0, z1 = cz < G - 1 ? cz + 1 : G - 1;

    const float* pxb = px + (size_t)b * N;
    const float* pyb = py + (size_t)b * N;
    const float* pzb = pz + (size_t)b * N;
    const float* fsb = fs + (size_t)b * N;

    // --- stage 27-cell neighborhood into LDS (9 contiguous x-row ranges) ---
    int dst = 0;
    for (int iz = z0; iz <= z1; ++iz) {
        for (int iy = y0; iy <= y1; ++iy) {
            const int row = (iz * G + iy) * G;
            const int beg = csb[row + x0];
            const int end = csb[row + x1 + 1];
            int take = end - beg;
            if (take > CAPC - dst) take = CAPC - dst;   // 12-sigma safe clamp
            for (int t = threadIdx.x; t < take; t += 256) {
                const int src = beg + t;
                s_cand[dst + t] =
                    make_float4(pxb[src], pyb[src], pzb[src], fsb[src]);
            }
            dst += take;
        }
    }
    const int ncand = dst;
    const int ncp = (ncand + 63) & ~63;  // sentinel-pad to multiple of 64
    for (int t = ncand + threadIdx.x; t < ncp; t += 256)
        s_cand[t] = make_float4(1e30f, 1e30f, 1e30f, 0.0f);
    __syncthreads();

    const int lane = threadIdx.x & 63;
    const int wave = threadIdx.x >> 6;
    float2* sel = s_sel[wave];
    float wsum = 0.0f;

    // --- one wave per query; waves stride the cell's bucket ---
    for (int qi = qbeg + wave; qi < qend; qi += WPB) {
        const float qx = pxb[qi], qy = pyb[qi], qz = pzb[qi], fi = fsb[qi];

        // scan LDS candidates, compact in-ball (d2, fd2)
        int cnt = 0;
        for (int base = 0; base < ncp; base += 64) {
            const float4 cd = s_cand[base + lane];
            const float dx = cd.x - qx, dy = cd.y - qy, dz = cd.z - qz;
            const float d2 = dx * dx + dy * dy + dz * dz;
            const bool in = (d2 <= r2);
            const unsigned long long m = __ballot(in);
            const int off = cnt + __popcll(m & ((1ULL << lane) - 1ULL));
            if (in && off < CAP) {
                const float fd = fi - cd.w;
                sel[off] = make_float2(d2, fd * fd);
            }
            cnt += __popcll(m);
        }
        const int M = cnt < CAP ? cnt : CAP;

        float qsum = 0.0f;
        if (M <= BQ_K) {
            // fewer than K in-ball: every neighbor counts (self-fill adds 0)
            if (lane < M) qsum = sel[lane].y;
        } else {
            const int Mp = (M + 63) & ~63;   // 64 or 128
            // pad buffer to Mp with +inf so invalid slots never rank < K
            for (int t = M + lane; t < Mp; t += 64)
                sel[t] = make_float2(1e30f, 0.0f);
            const float2 e0 = sel[lane];
            const float2 e1 = (Mp > 64) ? sel[64 + lane]
                                        : make_float2(1e30f, 0.0f);
            int r0 = 0, r1 = 0;
            for (int mc = 0; mc < Mp; mc += 64) {
                const float md = sel[mc + lane].x;
                #pragma unroll
                for (int mm = 0; mm < 64; ++mm) {
                    const float v = __shfl(md, mm, 64);
                    r0 += (v < e0.x) ? 1 : 0;
                    r1 += (v < e1.x) ? 1 : 0;
                }
            }
            if (r0 < BQ_K) qsum += e0.y;
            if (r1 < BQ_K) qsum += e1.y;
        }

        for (int o = 32; o > 0; o >>= 1) qsum += __shfl_down(qsum, o, 64);
        if (lane == 0) wsum += qsum;
    }

    if (lane == 0) s_wsum[wave] = wsum;
    __syncthreads();
    if (threadIdx.x == 0) {
        float bs = 0.0f;
        for (int w = 0; w < WPB; ++w) bs += s_wsum[w];
        atomicAdd(out, bs * scale);
    }
}

// ---------------- brute-force fallback (only if ws too small) --------------
#define FCAP 512
__global__ __launch_bounds__(256) void dirichlet_bf(
    const float* __restrict__ pos, const float* __restrict__ f,
    float* __restrict__ out, int B, int N, float r2, float scale)
{
    __shared__ float s_d2 [WPB][FCAP];
    __shared__ float s_fd2[WPB][FCAP];
    __shared__ float s_wavesum[WPB];

    const int lane = threadIdx.x & 63;
    const int wave = threadIdx.x >> 6;
    const int q = blockIdx.x * WPB + wave;
    const int b = q / N;
    const float* posb = pos + (size_t)b * N * 3;
    const float* fb   = f + (size_t)b * N;
    const float qx = posb[(size_t)(q - b * N) * 3 + 0];
    const float qy = posb[(size_t)(q - b * N) * 3 + 1];
    const float qz = posb[(size_t)(q - b * N) * 3 + 2];
    const float fi = f[q];

    int count = 0;
    for (int j0 = 0; j0 < N; j0 += 64) {
        const int j = j0 + lane;
        const float dx = posb[(size_t)j * 3 + 0] - qx;
        const float dy = posb[(size_t)j * 3 + 1] - qy;
        const float dz = posb[(size_t)j * 3 + 2] - qz;
        const float d2 = dx * dx + dy * dy + dz * dz;
        const bool in = (d2 <= r2);
        const unsigned long long mask = __ballot(in);
        const int off = count + __popcll(mask & ((1ULL << lane) - 1ULL));
        if (in && off < FCAP) {
            s_d2 [wave][off] = d2;
            const float fd = fi - fb[j];
            s_fd2[wave][off] = fd * fd;
        }
        count += __popcll(mask);
    }
    const int M = count < FCAP ? count : FCAP;
    __syncthreads();

    float sum = 0.0f;
    if (M <= BQ_K) {
        for (int e = lane; e < M; e += 64) sum += s_fd2[wave][e];
    } else {
        for (int e = lane; e < M; e += 64) {
            const float d2e = s_d2[wave][e];
            int rank = 0;
            for (int m = 0; m < M; ++m)
                rank += (s_d2[wave][m] < d2e) ? 1 : 0;
            if (rank < BQ_K) sum += s_fd2[wave][e];
        }
    }
    for (int o = 32; o > 0; o >>= 1) sum += __shfl_down(sum, o, 64);
    if (lane == 0) s_wavesum[wave] = sum;
    __syncthreads();
    if (threadIdx.x == 0) {
        float bs = 0.0f;
        for (int w = 0; w < WPB; ++w) bs += s_wavesum[w];
        atomicAdd(out, bs * scale);
    }
}

extern "C" void kernel_launch(void* const* d_in, const int* in_sizes, int n_in,
                              void* d_out, int out_size, void* d_ws, size_t ws_size,
                              hipStream_t stream) {
    const float* pos = (const float*)d_in[0];  // [B,N,3]
    const float* f   = (const float*)d_in[1];  // [B,N]
    float* out = (float*)d_out;

    const int N = 4096;
    const int B = in_sizes[1] / N;  // 8
    const float r2 = 0.15f * 0.15f;
    const float scale = 0.5f / (float)((long long)B * N);
    const int total = B * N;

    size_t n_cnt = (size_t)B * NC;
    size_t n_cs  = (size_t)B * (NC + 1);
    size_t need  = (n_cnt + n_cs + 4 * (size_t)total) * sizeof(int);

    if (ws_size < need) {
        dl_init<<<1, 64, 0, stream>>>((int*)d_ws, out, 0);
        dirichlet_bf<<<total / WPB, 256, 0, stream>>>(pos, f, out, B, N, r2, scale);
        return;
    }

    int*   cnt = (int*)d_ws;
    int*   cs  = cnt + n_cnt;
    float* px  = (float*)(cs + n_cs);
    float* py  = px + total;
    float* pz  = py + total;
    float* fs  = pz + total;

    dl_init   <<<(B * NC + 255) / 256, 256, 0, stream>>>(cnt, out, B * NC);
    dl_count  <<<(total + 255) / 256, 256, 0, stream>>>(pos, cnt, B, N);
    dl_prefix <<<B, 64, 0, stream>>>(cnt, cs, B);
    dl_scatter<<<(total + 255) / 256, 256, 0, stream>>>(pos, f, cnt, px, py, pz, fs, B, N);
    dl_main   <<<B * NC, 256, 0, stream>>>(cs, px, py, pz, fs, out, N, r2, scale);
}

// Round 4
// 117.254 us; speedup vs baseline: 2.0708x; 1.1233x over previous
//
#include <hip/hip_runtime.h>

// DirichletLoss: ball-query (r=0.15, K=32) + 0.5*mean_i sum_k (f_i - f_nei)^2
// pos: [B,N,3] f32, f: [B,N] f32, out: scalar f32.
//
// R4: fixed-stride bucket grid (6^3 cells, CMAX=56 float4 slots per cell;
// cell occupancy 19 +- 4.3, +8.5 sigma) so binning is ONE kernel: scatter with
// atomic per-cell cursor. Zeroing via hipMemsetAsync (graph-capturable).
// dl_main: one workgroup per (batch,cell); wave 0 shuffle-scans the 27
// neighbor-cell counts into an LDS prefix, whole block stages candidates into
// LDS float4 via binary search over the prefix; each wave takes one query
// from the center cell's staged points, scans LDS, ballot-compacts (d2,fd2),
// rank-selects K smallest d2 with register-broadcast (specialized M<=32 /
// M<=64 / M<=128 paths), reduces, one atomicAdd per block.
//
// Tie-break by index dropped (fp32 d2 ties at the K boundary: ~measure zero,
// R3 passed with absmax 0). In-ball cap 128 = +9.3 sigma (M = 58 +- 7.6).

#define BQ_K 32
#define CAP 128            // per-wave in-ball buffer
#define WPB 4              // waves per block (block = 256)
#define G 6
#define NC (G * G * G)     // 216 cells
#define CMAX 56            // bucket slots per cell
#define CAPC 832           // staged neighborhood cap (mean 512, sd 21)

__device__ __forceinline__ int cell_coord(float x) {
    int c = (int)(x * (float)G);
    return c < 0 ? 0 : (c > G - 1 ? G - 1 : c);
}

// one pass: bin every point into its cell's fixed-stride bucket
__global__ void dl_scatter(const float* __restrict__ pos, const float* __restrict__ f,
                           int* __restrict__ cnt, float4* __restrict__ buck,
                           int B, int N) {
    int t = blockIdx.x * blockDim.x + threadIdx.x;
    if (t >= B * N) return;
    int b = t / N;
    float x = pos[(size_t)t * 3 + 0];
    float y = pos[(size_t)t * 3 + 1];
    float z = pos[(size_t)t * 3 + 2];
    int c = (cell_coord(z) * G + cell_coord(y)) * G + cell_coord(x);
    int idx = b * NC + c;
    int slot = atomicAdd(&cnt[idx], 1);
    if (slot < CMAX) buck[(size_t)idx * CMAX + slot] = make_float4(x, y, z, f[t]);
}

__global__ __launch_bounds__(256) void dl_main(
    const int* __restrict__ cnt, const float4* __restrict__ buck,
    float* __restrict__ out, float r2, float scale)
{
    __shared__ float4 s_cand[CAPC + 64];
    __shared__ float2 s_sel[WPB][CAP];
    __shared__ int    s_off[28];
    __shared__ int    s_src[27];
    __shared__ float  s_wsum[WPB];

    const int bc = blockIdx.x;           // b*NC + c
    const int b  = bc / NC;
    const int c  = bc - b * NC;
    const int cx = c % G, cy = (c / G) % G, cz = c / (G * G);

    const int lane = threadIdx.x & 63;
    const int wave = threadIdx.x >> 6;

    // --- wave 0: gather 27 neighbor-cell counts, exclusive prefix in LDS ---
    if (wave == 0) {
        int v = 0, src = 0;
        if (lane < 27) {
            const int dx = lane % 3 - 1, dy = (lane / 3) % 3 - 1, dz = lane / 9 - 1;
            const int nx = cx + dx, ny = cy + dy, nz = cz + dz;
            if (nx >= 0 && nx < G && ny >= 0 && ny < G && nz >= 0 && nz < G) {
                const int idx = b * NC + (nz * G + ny) * G + nx;
                const int cc = cnt[idx];
                v = cc < CMAX ? cc : CMAX;
                src = idx * CMAX;
            }
        }
        int x = v;
        for (int o = 1; o < 32; o <<= 1) {
            int y = __shfl_up(x, o, 64);
            if (lane >= o) x += y;
        }
        const int excl = x - v;
        if (lane < 27) {
            s_off[lane] = excl < CAPC ? excl : CAPC;
            s_src[lane] = src;
        }
        if (lane == 26) s_off[27] = x < CAPC ? x : CAPC;
    }
    __syncthreads();

    const int ncand = s_off[27];
    const int ncp = (ncand + 63) & ~63;   // sentinel-pad to multiple of 64
    const int qoff = s_off[13];           // center cell's staged range
    const int qcnt = s_off[14] - s_off[13];

    // --- stage candidates into LDS (binary search over 27-range prefix) ---
    for (int d = threadIdx.x; d < ncp; d += 256) {
        if (d < ncand) {
            int lo = 0, hi = 27;
            while (hi - lo > 1) {
                const int mid = (lo + hi) >> 1;
                if (s_off[mid] <= d) lo = mid; else hi = mid;
            }
            s_cand[d] = buck[(size_t)s_src[lo] + (d - s_off[lo])];
        } else {
            s_cand[d] = make_float4(1e30f, 1e30f, 1e30f, 0.0f);
        }
    }
    __syncthreads();

    float2* sel = s_sel[wave];
    float wsum = 0.0f;

    // --- one wave per query; waves stride the center cell's points ---
    for (int qi = wave; qi < qcnt; qi += WPB) {
        const float4 qp = s_cand[qoff + qi];   // wave-uniform LDS broadcast
        const float qx = qp.x, qy = qp.y, qz = qp.z, fi = qp.w;

        // scan LDS candidates, compact in-ball (d2, fd2)
        int cin = 0;
        for (int base = 0; base < ncp; base += 64) {
            const float4 cd = s_cand[base + lane];
            const float dx = cd.x - qx, dy = cd.y - qy, dz = cd.z - qz;
            const float d2 = fmaf(dx, dx, fmaf(dy, dy, dz * dz));
            const bool in = (d2 <= r2);
            const unsigned long long m = __ballot(in);
            const int off = cin + __popcll(m & ((1ULL << lane) - 1ULL));
            if (in && off < CAP) {
                const float fd = fi - cd.w;
                sel[off] = make_float2(d2, fd * fd);
            }
            cin += __popcll(m);
        }
        const int M = cin < CAP ? cin : CAP;

        const float2 e0 = (lane < M) ? sel[lane] : make_float2(1e30f, 0.0f);
        float qsum = 0.0f;
        if (M <= BQ_K) {
            qsum = e0.y;                       // all in-ball neighbors count
        } else if (M <= 64) {
            int r0 = 0;
            #pragma unroll
            for (int mm = 0; mm < 64; ++mm) {
                const float v = __shfl(e0.x, mm, 64);
                r0 += (v < e0.x) ? 1 : 0;
            }
            if (r0 < BQ_K) qsum = e0.y;
        } else {
            const float2 e1 = (64 + lane < M) ? sel[64 + lane]
                                              : make_float2(1e30f, 0.0f);
            int r0 = 0, r1 = 0;
            #pragma unroll
            for (int mm = 0; mm < 64; ++mm) {
                const float v0 = __shfl(e0.x, mm, 64);
                const float v1 = __shfl(e1.x, mm, 64);
                r0 += (v0 < e0.x) ? 1 : 0;
                r0 += (v1 < e0.x) ? 1 : 0;
                r1 += (v0 < e1.x) ? 1 : 0;
                r1 += (v1 < e1.x) ? 1 : 0;
            }
            if (r0 < BQ_K) qsum = e0.y;
            if (r1 < BQ_K) qsum += e1.y;
        }

        for (int o = 32; o > 0; o >>= 1) qsum += __shfl_down(qsum, o, 64);
        if (lane == 0) wsum += qsum;
    }

    if (lane == 0) s_wsum[wave] = wsum;
    __syncthreads();
    if (threadIdx.x == 0) {
        float bs = 0.0f;
        for (int w = 0; w < WPB; ++w) bs += s_wsum[w];
        atomicAdd(out, bs * scale);
    }
}

// ---------------- brute-force fallback (only if ws too small) --------------
#define FCAP 512
__global__ __launch_bounds__(256) void dirichlet_bf(
    const float* __restrict__ pos, const float* __restrict__ f,
    float* __restrict__ out, int B, int N, float r2, float scale)
{
    __shared__ float s_d2 [WPB][FCAP];
    __shared__ float s_fd2[WPB][FCAP];
    __shared__ float s_wavesum[WPB];

    const int lane = threadIdx.x & 63;
    const int wave = threadIdx.x >> 6;
    const int q = blockIdx.x * WPB + wave;
    const int b = q / N;
    const float* posb = pos + (size_t)b * N * 3;
    const float* fb   = f + (size_t)b * N;
    const float qx = posb[(size_t)(q - b * N) * 3 + 0];
    const float qy = posb[(size_t)(q - b * N) * 3 + 1];
    const float qz = posb[(size_t)(q - b * N) * 3 + 2];
    const float fi = f[q];

    int count = 0;
    for (int j0 = 0; j0 < N; j0 += 64) {
        const int j = j0 + lane;
        const float dx = posb[(size_t)j * 3 + 0] - qx;
        const float dy = posb[(size_t)j * 3 + 1] - qy;
        const float dz = posb[(size_t)j * 3 + 2] - qz;
        const float d2 = dx * dx + dy * dy + dz * dz;
        const bool in = (d2 <= r2);
        const unsigned long long mask = __ballot(in);
        const int off = count + __popcll(mask & ((1ULL << lane) - 1ULL));
        if (in && off < FCAP) {
            s_d2 [wave][off] = d2;
            const float fd = fi - fb[j];
            s_fd2[wave][off] = fd * fd;
        }
        count += __popcll(mask);
    }
    const int M = count < FCAP ? count : FCAP;
    __syncthreads();

    float sum = 0.0f;
    if (M <= BQ_K) {
        for (int e = lane; e < M; e += 64) sum += s_fd2[wave][e];
    } else {
        for (int e = lane; e < M; e += 64) {
            const float d2e = s_d2[wave][e];
            int rank = 0;
            for (int m = 0; m < M; ++m)
                rank += (s_d2[wave][m] < d2e) ? 1 : 0;
            if (rank < BQ_K) sum += s_fd2[wave][e];
        }
    }
    for (int o = 32; o > 0; o >>= 1) sum += __shfl_down(sum, o, 64);
    if (lane == 0) s_wavesum[wave] = sum;
    __syncthreads();
    if (threadIdx.x == 0) {
        float bs = 0.0f;
        for (int w = 0; w < WPB; ++w) bs += s_wavesum[w];
        atomicAdd(out, bs * scale);
    }
}

extern "C" void kernel_launch(void* const* d_in, const int* in_sizes, int n_in,
                              void* d_out, int out_size, void* d_ws, size_t ws_size,
                              hipStream_t stream) {
    const float* pos = (const float*)d_in[0];  // [B,N,3]
    const float* f   = (const float*)d_in[1];  // [B,N]
    float* out = (float*)d_out;

    const int N = 4096;
    const int B = in_sizes[1] / N;  // 8
    const float r2 = 0.15f * 0.15f;
    const float scale = 0.5f / (float)((long long)B * N);
    const int total = B * N;

    const size_t cnt_bytes  = (size_t)B * NC * sizeof(int);       // 6912 (16-aligned)
    const size_t buck_bytes = (size_t)B * NC * CMAX * sizeof(float4);
    const size_t need = cnt_bytes + buck_bytes;                   // ~1.56 MB

    hipMemsetAsync(out, 0, sizeof(float), stream);

    if (ws_size < need) {
        dirichlet_bf<<<total / WPB, 256, 0, stream>>>(pos, f, out, B, N, r2, scale);
        return;
    }

    int*    cnt  = (int*)d_ws;
    float4* buck = (float4*)((char*)d_ws + cnt_bytes);

    hipMemsetAsync(cnt, 0, cnt_bytes, stream);
    dl_scatter<<<(total + 255) / 256, 256, 0, stream>>>(pos, f, cnt, buck, B, N);
    dl_main   <<<B * NC, 256, 0, stream>>>(cnt, buck, out, r2, scale);
}

// Round 5
// 99.207 us; speedup vs baseline: 2.4475x; 1.1819x over previous
//
#include <hip/hip_runtime.h>

// DirichletLoss: ball-query (r=0.15, K=32) + 0.5*mean_i sum_k (f_i - f_nei)^2
// pos: [B,N,3] f32, f: [B,N] f32, out: scalar f32.
//
// R5: single fused kernel (plus one hipMemsetAsync for out). One workgroup
// per (batch, cell) of a 6^3 conceptual grid (cell 1/6 >= r). Phase A: the
// block scans ALL N points of its batch (L2-resident, re-read by 216 blocks),
// filters "cell coord within +-1 of mine", ballot-compacts into an LDS
// float4 candidate buffer via a shared LDS cursor; center-cell points also
// get pushed to an LDS query list. Phase B: one wave per query — scan LDS
// candidates, ballot-compact in-ball (d2, fd2) into a per-wave buffer,
// rank-select K smallest d2 via wave-uniform LDS broadcast reads (looped to
// M, not padded), accumulate per-lane, reduce once, one atomicAdd per block.
//
// No d_ws needed. Tie-break by index dropped (fp32 d2 ties at the K boundary
// are measure-zero; R3/R4 passed with absmax 0). Capacity proofs (Binomial):
// neighborhood <= 832 (mean 512, sd 21, +15sigma); in-ball M <= 128
// (mean 58, sd 7.6, +9.3sigma); queries/cell <= 64 (mean 19, sd 4.3, +10s).

#define BQ_K 32
#define CAP 128            // per-wave in-ball buffer
#define WPB 4              // waves per block (block = 256)
#define G 6
#define NC (G * G * G)     // 216 cells
#define CAPC 832           // staged neighborhood cap
#define QMAX 64            // center-cell query cap

__device__ __forceinline__ int cell_coord(float x) {
    int c = (int)(x * (float)G);
    return c < 0 ? 0 : (c > G - 1 ? G - 1 : c);
}

__global__ __launch_bounds__(256) void dl_fused(
    const float* __restrict__ pos, const float* __restrict__ f,
    float* __restrict__ out, int N, float r2, float scale)
{
    __shared__ float4 s_cand[CAPC + 64];
    __shared__ float2 s_sel[WPB][CAP];
    __shared__ int    s_q[QMAX];
    __shared__ int    s_ncand, s_nq;
    __shared__ float  s_wsum[WPB];

    const int bc = blockIdx.x;           // b*NC + c
    const int b  = bc / NC;
    const int c  = bc - b * NC;
    const int cx = c % G, cy = (c / G) % G, cz = c / (G * G);

    const int lane = threadIdx.x & 63;
    const int wave = threadIdx.x >> 6;

    if (threadIdx.x == 0) { s_ncand = 0; s_nq = 0; }
    __syncthreads();

    const float* posb = pos + (size_t)b * N * 3;
    const float* fb   = f   + (size_t)b * N;

    // --- Phase A: scan all N points, filter 3x3x3 cell-neighborhood,
    //     ballot-compact into s_cand (shared cursor), queries into s_q ---
    const int per = N >> 2;              // points per wave (N % 256 == 0)
    const int wbeg = wave * per;
    for (int j0 = 0; j0 < per; j0 += 64) {
        const int j = wbeg + j0 + lane;
        const float x = posb[(size_t)j * 3 + 0];
        const float y = posb[(size_t)j * 3 + 1];
        const float z = posb[(size_t)j * 3 + 2];
        const int ccx = cell_coord(x), ccy = cell_coord(y), ccz = cell_coord(z);
        const bool in = (unsigned)(ccx - cx + 1) <= 2u &&
                        (unsigned)(ccy - cy + 1) <= 2u &&
                        (unsigned)(ccz - cz + 1) <= 2u;
        const unsigned long long m = __ballot(in);
        const int nh = __popcll(m);
        int base = 0;
        if (lane == 0 && nh) base = atomicAdd(&s_ncand, nh);
        base = __shfl(base, 0, 64);
        if (in) {
            const int off = base + __popcll(m & ((1ULL << lane) - 1ULL));
            if (off < CAPC) {
                s_cand[off] = make_float4(x, y, z, fb[j]);
                if (ccx == cx && ccy == cy && ccz == cz) {
                    const int qs = atomicAdd(&s_nq, 1);
                    if (qs < QMAX) s_q[qs] = off;
                }
            }
        }
    }
    __syncthreads();

    const int ncand = s_ncand < CAPC ? s_ncand : CAPC;
    const int nq    = s_nq < QMAX ? s_nq : QMAX;
    const int ncp   = (ncand + 63) & ~63;    // sentinel-pad to multiple of 64
    for (int t = ncand + threadIdx.x; t < ncp; t += 256)
        s_cand[t] = make_float4(1e30f, 1e30f, 1e30f, 0.0f);
    __syncthreads();

    float2* sel = s_sel[wave];
    float wsum = 0.0f;                   // per-lane accumulator

    // --- Phase B: one wave per query ---
    for (int qi = wave; qi < nq; qi += WPB) {
        const float4 qp = s_cand[s_q[qi]];   // wave-uniform LDS broadcast
        const float qx = qp.x, qy = qp.y, qz = qp.z, fi = qp.w;

        // scan staged candidates, compact in-ball (d2, fd2)
        int cin = 0;
        for (int basej = 0; basej < ncp; basej += 64) {
            const float4 cd = s_cand[basej + lane];
            const float dx = cd.x - qx, dy = cd.y - qy, dz = cd.z - qz;
            const float d2 = fmaf(dx, dx, fmaf(dy, dy, dz * dz));
            const bool inb = (d2 <= r2);
            const unsigned long long mm = __ballot(inb);
            const int off = cin + __popcll(mm & ((1ULL << lane) - 1ULL));
            if (inb && off < CAP) {
                const float fd = fi - cd.w;
                sel[off] = make_float2(d2, fd * fd);
            }
            cin += __popcll(mm);
        }
        const int M = cin < CAP ? cin : CAP;

        if (M <= BQ_K) {
            if (lane < M) wsum += sel[lane].y;
        } else {
            // rank both register-resident entries against all M keys via
            // wave-uniform (broadcast, conflict-free) LDS reads; iterations
            // are independent -> fully pipelined ds_read_b32 stream.
            const float2 e0 = (lane < M) ? sel[lane]
                                         : make_float2(1e30f, 0.0f);
            const float2 e1 = (64 + lane < M) ? sel[64 + lane]
                                              : make_float2(1e30f, 0.0f);
            int r0 = 0, r1 = 0;
            for (int mi = 0; mi < M; ++mi) {
                const float v = sel[mi].x;
                r0 += (v < e0.x) ? 1 : 0;
                r1 += (v < e1.x) ? 1 : 0;
            }
            if (r0 < BQ_K) wsum += e0.y;
            if (r1 < BQ_K) wsum += e1.y;   // e1 sentinel 1e30 -> r1 = M >= K
        }
    }

    // --- single reduction at the end ---
    for (int o = 32; o > 0; o >>= 1) wsum += __shfl_down(wsum, o, 64);
    if (lane == 0) s_wsum[wave] = wsum;
    __syncthreads();
    if (threadIdx.x == 0) {
        const float bs = s_wsum[0] + s_wsum[1] + s_wsum[2] + s_wsum[3];
        atomicAdd(out, bs * scale);
    }
}

extern "C" void kernel_launch(void* const* d_in, const int* in_sizes, int n_in,
                              void* d_out, int out_size, void* d_ws, size_t ws_size,
                              hipStream_t stream) {
    const float* pos = (const float*)d_in[0];  // [B,N,3]
    const float* f   = (const float*)d_in[1];  // [B,N]
    float* out = (float*)d_out;

    const int N = 4096;
    const int B = in_sizes[1] / N;  // 8
    const float r2 = 0.15f * 0.15f;
    const float scale = 0.5f / (float)((long long)B * N);

    hipMemsetAsync(out, 0, sizeof(float), stream);
    dl_fused<<<B * NC, 256, 0, stream>>>(pos, f, out, N, r2, scale);
}

// Round 6
// 93.106 us; speedup vs baseline: 2.6079x; 1.0655x over previous
//
#include <hip/hip_runtime.h>

// DirichletLoss: ball-query (r=0.15, K=32) + 0.5*mean_i sum_k (f_i - f_nei)^2
// pos: [B,N,3] f32, f: [B,N] f32, out: scalar f32.
//
// R6: single fused kernel (+ one hipMemsetAsync for out). One workgroup per
// (batch, cell) of a 6^3 grid (cell 1/6 >= r). Phase A: block scans all N
// points of its batch (L2-resident), filters "cell coord within +-1 of
// mine", ballot-compacts into an LDS float4 candidate buffer (shared LDS
// cursor); center-cell points also recorded as queries. Phase B: one wave
// per query — scan LDS candidates, ballot-compact in-ball (d2, fd2) into a
// per-wave LDS buffer (transport only), reload as 2 register entries/lane,
// then select the K-th-smallest d2 threshold via 26-iteration ballot
// bisection (wave-uniform scalar control, no LDS reads) and sum fd2 below
// it. Per-lane accumulate, single reduce, one atomicAdd per block.
//
// Tie-break by index dropped (fp32 d2 ties at the K boundary are measure
// zero; R3-R5 passed with absmax 0). Bisection residual ~r2*2^-26 ~ 3e-10:
// misclassification needs two distinct d2 within that gap straddling rank K
// -> error <= fd2 * 0.5/32768 ~ 1e-5 << 0.61 threshold.
//
// Capacity proofs (Binomial tails): neighborhood <= 832 (mean 512, sd 21,
// +15sigma); in-ball M <= 128 (mean 58, sd 7.6, +9.3sigma); queries/cell
// <= 64 (mean 19, sd 4.3, +10sigma).

#define BQ_K 32
#define CAP 128            // per-wave in-ball buffer
#define WPB 4              // waves per block (block = 256)
#define G 6
#define NC (G * G * G)     // 216 cells
#define CAPC 832           // staged neighborhood cap
#define QMAX 64            // center-cell query cap

__device__ __forceinline__ int cell_coord(float x) {
    int c = (int)(x * (float)G);
    return c < 0 ? 0 : (c > G - 1 ? G - 1 : c);
}

__global__ __launch_bounds__(256) void dl_fused(
    const float* __restrict__ pos, const float* __restrict__ f,
    float* __restrict__ out, int N, float r2, float scale)
{
    __shared__ float4 s_cand[CAPC + 64];
    __shared__ float2 s_sel[WPB][CAP];
    __shared__ int    s_q[QMAX];
    __shared__ int    s_ncand, s_nq;
    __shared__ float  s_wsum[WPB];

    const int bc = blockIdx.x;           // b*NC + c
    const int b  = bc / NC;
    const int c  = bc - b * NC;
    const int cx = c % G, cy = (c / G) % G, cz = c / (G * G);

    const int lane = threadIdx.x & 63;
    const int wave = threadIdx.x >> 6;

    if (threadIdx.x == 0) { s_ncand = 0; s_nq = 0; }
    __syncthreads();

    const float* posb = pos + (size_t)b * N * 3;
    const float* fb   = f   + (size_t)b * N;

    // --- Phase A: scan all N points, filter 3x3x3 cell-neighborhood,
    //     ballot-compact into s_cand (shared cursor), queries into s_q ---
    const int per = N >> 2;              // points per wave (N % 256 == 0)
    const int wbeg = wave * per;
    for (int j0 = 0; j0 < per; j0 += 64) {
        const int j = wbeg + j0 + lane;
        const float x = posb[(size_t)j * 3 + 0];
        const float y = posb[(size_t)j * 3 + 1];
        const float z = posb[(size_t)j * 3 + 2];
        const float fj = fb[j];          // unconditional: off the dep chain
        const int ccx = cell_coord(x), ccy = cell_coord(y), ccz = cell_coord(z);
        const bool in = (unsigned)(ccx - cx + 1) <= 2u &&
                        (unsigned)(ccy - cy + 1) <= 2u &&
                        (unsigned)(ccz - cz + 1) <= 2u;
        const unsigned long long m = __ballot(in);
        const int nh = __popcll(m);
        int base = 0;
        if (lane == 0 && nh) base = atomicAdd(&s_ncand, nh);
        base = __shfl(base, 0, 64);
        if (in) {
            const int off = base + __popcll(m & ((1ULL << lane) - 1ULL));
            if (off < CAPC) {
                s_cand[off] = make_float4(x, y, z, fj);
                if (ccx == cx && ccy == cy && ccz == cz) {
                    const int qs = atomicAdd(&s_nq, 1);
                    if (qs < QMAX) s_q[qs] = off;
                }
            }
        }
    }
    __syncthreads();

    const int ncand = s_ncand < CAPC ? s_ncand : CAPC;
    const int nq    = s_nq < QMAX ? s_nq : QMAX;
    const int ncp   = (ncand + 63) & ~63;    // sentinel-pad to multiple of 64
    for (int t = ncand + threadIdx.x; t < ncp; t += 256)
        s_cand[t] = make_float4(1e30f, 1e30f, 1e30f, 0.0f);
    __syncthreads();

    float2* sel = s_sel[wave];
    float wsum = 0.0f;                   // per-lane accumulator

    // --- Phase B: one wave per query ---
    for (int qi = wave; qi < nq; qi += WPB) {
        const float4 qp = s_cand[s_q[qi]];   // wave-uniform LDS broadcast
        const float qx = qp.x, qy = qp.y, qz = qp.z, fi = qp.w;

        // scan staged candidates, compact in-ball (d2, fd2) into sel
        int cin = 0;
        for (int basej = 0; basej < ncp; basej += 64) {
            const float4 cd = s_cand[basej + lane];
            const float dx = cd.x - qx, dy = cd.y - qy, dz = cd.z - qz;
            const float d2 = fmaf(dx, dx, fmaf(dy, dy, dz * dz));
            const bool inb = (d2 <= r2);
            const unsigned long long mm = __ballot(inb);
            const int off = cin + __popcll(mm & ((1ULL << lane) - 1ULL));
            if (inb && off < CAP) {
                const float fd = fi - cd.w;
                sel[off] = make_float2(d2, fd * fd);
            }
            cin += __popcll(mm);
        }
        const int M = cin < CAP ? cin : CAP;

        // reload as two register-resident entries per lane (sentinel-padded)
        const float2 e0 = (lane < M) ? sel[lane]
                                     : make_float2(1e30f, 0.0f);
        const float2 e1 = (64 + lane < M) ? sel[64 + lane]
                                          : make_float2(1e30f, 0.0f);

        if (M <= BQ_K) {
            wsum += e0.y + e1.y;         // all in-ball count; sentinels add 0
        } else {
            // K-th smallest d2 via ballot bisection; scalar (uniform) control
            float lo = 0.0f, hi = r2 * 1.000001f;
            #pragma unroll
            for (int it = 0; it < 26; ++it) {
                const float mid = 0.5f * (lo + hi);
                const int cnt = __popcll(__ballot(e0.x < mid)) +
                                __popcll(__ballot(e1.x < mid));
                if (cnt >= BQ_K) hi = mid; else lo = mid;
            }
            if (e0.x < hi) wsum += e0.y;
            if (e1.x < hi) wsum += e1.y;
        }
    }

    // --- single reduction at the end ---
    for (int o = 32; o > 0; o >>= 1) wsum += __shfl_down(wsum, o, 64);
    if (lane == 0) s_wsum[wave] = wsum;
    __syncthreads();
    if (threadIdx.x == 0) {
        const float bs = s_wsum[0] + s_wsum[1] + s_wsum[2] + s_wsum[3];
        atomicAdd(out, bs * scale);
    }
}

extern "C" void kernel_launch(void* const* d_in, const int* in_sizes, int n_in,
                              void* d_out, int out_size, void* d_ws, size_t ws_size,
                              hipStream_t stream) {
    const float* pos = (const float*)d_in[0];  // [B,N,3]
    const float* f   = (const float*)d_in[1];  // [B,N]
    float* out = (float*)d_out;

    const int N = 4096;
    const int B = in_sizes[1] / N;  // 8
    const float r2 = 0.15f * 0.15f;
    const float scale = 0.5f / (float)((long long)B * N);

    hipMemsetAsync(out, 0, sizeof(float), stream);
    dl_fused<<<B * NC, 256, 0, stream>>>(pos, f, out, N, r2, scale);
}